// Round 12
// baseline (269.004 us; speedup 1.0000x reference)
//
#include <hip/hip_runtime.h>
#include <hip/hip_bf16.h>

typedef __bf16 bf16;
typedef __attribute__((ext_vector_type(8))) __bf16 bf16x8;
typedef __attribute__((ext_vector_type(4))) __bf16 bf16x4;
typedef __attribute__((ext_vector_type(4))) float f32x4;
typedef __attribute__((ext_vector_type(16))) float f32x16;
typedef __attribute__((ext_vector_type(4))) int int4v;

#define TSEQ 2048
#define DMODEL 1024
#define NHEAD 16
#define DKH 64
#define BATCH 2
#define NQKV 3072
#define QKROW 2048   // QK buffer row stride (V redirected to VT)

// async global->LDS, 16B per lane; LDS dest = wave-uniform base + lane*16
typedef __attribute__((address_space(1))) const void gv_t;
typedef __attribute__((address_space(3))) void sv_t;
__device__ __forceinline__ void gll16(const bf16* g, bf16* s) {
    __builtin_amdgcn_global_load_lds((gv_t*)g, (sv_t*)s, 16, 0, 0);
}
// counted vmcnt wait (lgkmcnt=15, expcnt=7 untouched). __syncthreads does NOT
// drain DMA vmcnt on this toolchain -> explicit wait required.
#define WAIT_VM(n) __builtin_amdgcn_s_waitcnt(0x0F70 | (n))

// v_cvt_pk_bf16_f32: D.lo = bf16(s0), D.hi = bf16(s1)
__device__ __forceinline__ unsigned cvtpk(float lo, float hi) {
    unsigned d;
    asm("v_cvt_pk_bf16_f32 %0, %1, %2" : "=v"(d) : "v"(lo), "v"(hi));
    return d;
}

// ------------------------------------------------------- fused prep kernel
#define PREP_CONV 4096   // NX / (256*4)
#define PREP_TW   4096
#define PREP_GRID (PREP_CONV + PREP_TW + 12)
__global__ __launch_bounds__(256) void prep(
    const float* __restrict__ x,
    const float* __restrict__ Wq, const float* __restrict__ Wk,
    const float* __restrict__ Wv, const float* __restrict__ Wo,
    const float* __restrict__ bq, const float* __restrict__ bk,
    const float* __restrict__ bv,
    bf16* __restrict__ xb, bf16* __restrict__ WT, float* __restrict__ biasO)
{
    __shared__ float t[32][33];
    int bid = blockIdx.x;
    const int tid = threadIdx.x;
    if (bid < PREP_CONV) {                       // ---- convert
        int i = (bid * 256 + tid) * 4;
        f32x4 v = *(const f32x4*)(x + i);
        bf16x4 o;
#pragma unroll
        for (int j = 0; j < 4; ++j) o[j] = (bf16)v[j];
        *(bf16x4*)(xb + i) = o;
        return;
    }
    bid -= PREP_CONV;
    if (bid < PREP_TW) {                         // ---- transpose W (32x32 tile)
        int z = bid >> 10;
        int by = ((bid >> 5) & 31) * 32, bx = (bid & 31) * 32;
        const float* W = z == 0 ? Wq : z == 1 ? Wk : z == 2 ? Wv : Wo;
        bf16* T = WT + (size_t)z * DMODEL * DMODEL;
        int tx = tid & 31, ty = tid >> 5;
#pragma unroll
        for (int i = 0; i < 4; ++i)
            t[ty + i * 8][tx] = W[(size_t)(by + ty + i * 8) * DMODEL + bx + tx];
        __syncthreads();
#pragma unroll
        for (int i = 0; i < 4; ++i)
            T[(size_t)(bx + ty + i * 8) * DMODEL + by + tx] = (bf16)t[tx][ty + i * 8];
        return;
    }
    bid -= PREP_TW;
    int i = bid * 256 + tid;                     // ---- bias concat, 0..3071
    float v = i < 1024 ? bq[i] : i < 2048 ? bk[i - 1024] : bv[i - 2048];
    biasO[i] = v;
}

// ---------------------------------------------------------------- GEMM + bias
// (r11 body) BK=64, 2-buffer, XOR-swizzled LDS tiles, XCD-chunked mapping.
// FUSE_VT: n0>=2048 writes V-part transposed to VT; Q,K go to C with ldc.
template <typename OutT, int NW_N, bool FUSE_VT>
__global__ __launch_bounds__(256) void gemm_bias_kernel(
    const bf16* __restrict__ A, const bf16* __restrict__ BT,
    const float* __restrict__ bias, OutT* __restrict__ C, int ldc,
    bf16* __restrict__ VT)
{
    constexpr int BN    = NW_N * 64;
    constexpr int MW    = 4 / NW_N;
    constexpr int WROWS = 128 / MW;
    constexpr int FM    = WROWS / 16;
    constexpr int BK    = 64;
    constexpr int ASZ   = 128 * BK;
    constexpr int BSZ   = BN * BK;
    constexpr int BNP   = BN + 4;
    constexpr int TST   = 136;
    constexpr int EPI   = sizeof(OutT) == 2 ? (FUSE_VT ? 128 * TST : 128 * BN)
                                            : 64 * BNP * 2;
    constexpr int STG   = 2 * ASZ + 2 * BSZ;
    constexpr int SMEM  = STG > EPI ? STG : EPI;
    __shared__ bf16 smem[SMEM];
    bf16* As0 = smem;
    bf16* Bs0 = smem + 2 * ASZ;

    const int tid = threadIdx.x;
    const int ln = tid & 63, wave = tid >> 6;
    const int wm = NW_N == 2 ? (wave >> 1) : wave;
    const int wn = NW_N == 2 ? (wave & 1) : 0;
    const int lr = ln & 15, quad = ln >> 4;

    constexpr int NBX = (NW_N == 2) ? 24 : 16;
    constexpr int CH  = (NW_N == 2) ? 96 : 64;
    const int wg  = blockIdx.x;
    const int lin = (wg & 7) * CH + (wg >> 3);
    const int m0  = (lin / NBX) * 128, n0 = (lin % NBX) * BN;

    f32x4 acc[FM][4] = {};

    const int srow = ln >> 3;
    const int scol = ((ln & 7) ^ srow) * 8;
    const bf16* Ag = A + (size_t)(m0 + wave * 32 + srow) * DMODEL + scol;
    const bf16* Bg = BT + (size_t)(n0 + (NW_N == 2 ? wave * 32 : wave * 16) + srow) * DMODEL + scol;

    auto stage = [&](int buf, int kk) {
        bf16* AsW = As0 + buf * ASZ + wave * (32 * BK);
#pragma unroll
        for (int l = 0; l < 4; ++l)
            gll16(Ag + (size_t)(l * 8) * DMODEL + kk, AsW + l * 8 * BK);
        if constexpr (NW_N == 2) {
            bf16* BsW = Bs0 + buf * BSZ + wave * (32 * BK);
#pragma unroll
            for (int l = 0; l < 4; ++l)
                gll16(Bg + (size_t)(l * 8) * DMODEL + kk, BsW + l * 8 * BK);
        } else {
            bf16* BsW = Bs0 + buf * BSZ + wave * (16 * BK);
#pragma unroll
            for (int l = 0; l < 2; ++l)
                gll16(Bg + (size_t)(l * 8) * DMODEL + kk, BsW + l * 8 * BK);
        }
    };

    constexpr int NT = DMODEL / BK;
    stage(0, 0);
    WAIT_VM(0);
    __syncthreads();
    const int swr = lr & 7;
    for (int kt = 0; kt < NT; ++kt) {
        if (kt + 1 < NT) stage((kt + 1) & 1, (kt + 1) * BK);
        const bf16* AsB = As0 + (kt & 1) * ASZ;
        const bf16* BsB = Bs0 + (kt & 1) * BSZ;
#pragma unroll
        for (int k2 = 0; k2 < 2; ++k2) {
            bf16x8 af[FM], bfr[4];
#pragma unroll
            for (int i = 0; i < FM; ++i)
                af[i] = *(const bf16x8*)(AsB + (wm * WROWS + i * 16 + lr) * BK +
                                         (((k2 * 4 + quad) ^ swr) * 8));
#pragma unroll
            for (int j = 0; j < 4; ++j)
                bfr[j] = *(const bf16x8*)(BsB + (wn * 64 + j * 16 + lr) * BK +
                                          (((k2 * 4 + quad) ^ swr) * 8));
#pragma unroll
            for (int i = 0; i < FM; ++i)
#pragma unroll
                for (int j = 0; j < 4; ++j)
                    acc[i][j] = __builtin_amdgcn_mfma_f32_16x16x32_bf16(
                        af[i], bfr[j], acc[i][j], 0, 0, 0);
        }
        WAIT_VM(0);
        __syncthreads();
    }

    if constexpr (sizeof(OutT) == 2) {
        if (FUSE_VT && n0 >= 2048) {
            bf16* Cs = smem;
#pragma unroll
            for (int j = 0; j < 4; ++j) {
                int nl = wn * 64 + j * 16 + lr;
                float bv = bias[n0 + nl];
#pragma unroll
                for (int i = 0; i < FM; ++i) {
                    int ml = wm * WROWS + i * 16 + quad * 4;
#pragma unroll
                    for (int r = 0; r < 4; ++r)
                        Cs[nl * TST + ml + r] = (bf16)(acc[i][j][r] + bv);
                }
            }
            __syncthreads();
            const int bb = m0 >> 11;
            const int tloc = m0 & 2047;
#pragma unroll
            for (int pp = 0; pp < 8; ++pp) {
                int dl = pp * 16 + (tid >> 4);
                int t0 = (tid & 15) * 8;
                bf16x8 v = *(const bf16x8*)(Cs + dl * TST + t0);
                *(bf16x8*)(VT + (size_t)(bb * 1024 + (n0 - 2048) + dl) * TSEQ +
                           tloc + t0) = v;
            }
            return;
        }
        bf16* Cs = smem;
#pragma unroll
        for (int j = 0; j < 4; ++j) {
            int nl = wn * 64 + j * 16 + lr;
            float bv = bias[n0 + nl];
#pragma unroll
            for (int i = 0; i < FM; ++i) {
                int ml = wm * WROWS + i * 16 + quad * 4;
#pragma unroll
                for (int r = 0; r < 4; ++r)
                    Cs[(ml + r) * BN + nl] = (bf16)(acc[i][j][r] + bv);
            }
        }
        __syncthreads();
        constexpr int LPR = BN / 8;
        constexpr int RPP = 256 / LPR;
        const int rr = tid / LPR, cc = (tid % LPR) * 8;
#pragma unroll
        for (int pp = 0; pp < 128 / RPP; ++pp) {
            int row = pp * RPP + rr;
            *(bf16x8*)(C + (size_t)(m0 + row) * ldc + n0 + cc) =
                *(const bf16x8*)(Cs + row * BN + cc);
        }
    } else {
        float* Cf = (float*)smem;
#pragma unroll
        for (int half = 0; half < 2; ++half) {
            if (((wm * WROWS) >> 6) == half) {
#pragma unroll
                for (int j = 0; j < 4; ++j) {
                    int nl = wn * 64 + j * 16 + lr;
                    float bv = bias[n0 + nl];
#pragma unroll
                    for (int i = 0; i < FM; ++i) {
                        int ml = wm * WROWS + i * 16 + quad * 4 - half * 64;
#pragma unroll
                        for (int r = 0; r < 4; ++r)
                            Cf[(ml + r) * BNP + nl] = acc[i][j][r] + bv;
                    }
                }
            }
            __syncthreads();
            constexpr int LPR = BN / 4;
            constexpr int RPP = 256 / LPR;
            const int rr = tid / LPR, cc = (tid % LPR) * 4;
#pragma unroll
            for (int pp = 0; pp < 64 / RPP; ++pp) {
                int row = pp * RPP + rr;
                *(f32x4*)(C + (size_t)(m0 + half * 64 + row) * ldc + n0 + cc) =
                    *(const f32x4*)(Cf + row * BNP + cc);
            }
            __syncthreads();
        }
    }
}

// ---------------------------------------------------------------- flash attn
// SPLIT-K over the chunk stream: fixed-max softmax has NO running max, so
// partial O and partial l are LINEAR -> the key stream of each pair
// (A=p, B=31-p) splits by chunk PARITY into two blocks (grid 1024). This
// breaks the 8-waves/CU grid cap (512 blocks was 2 waves/SIMD; VALUBusy
// pinned at 51%): 32KB LDS + launch_bounds(256,4) -> 4 blocks/CU = 16
// waves/CU, and parity-split work is uniform (~132 MFMA-weight/wave for
// EVERY block) so occupancy holds. Halves write unnormalized bf16 partials
// + f32 l partials; a combine kernel computes (O0+O1)/(l0+l1).
template <int KTN, bool MASKED>
__device__ __forceinline__ void tile_step(
    int kt0, int kc, int qabs,
    const bf16* __restrict__ Ksb, const bf16* __restrict__ Vsb,
    const bf16x8 qf[4], f32x16 oacc[2], float& lrow,
    int ln31, int hi, int sw)
{
    f32x16 st[KTN] = {};
    __builtin_amdgcn_s_setprio(1);
#pragma unroll
    for (int t = 0; t < KTN; ++t)
#pragma unroll
        for (int ks = 0; ks < 4; ++ks) {
            const bf16x8 ka = *(const bf16x8*)(
                Ksb + (ln31 + (kt0 + t) * 32) * 64 + (((2 * ks + hi) ^ sw) * 8));
            st[t] = __builtin_amdgcn_mfma_f32_32x32x16_bf16(ka, qf[ks], st[t], 0, 0, 0);
        }
    __builtin_amdgcn_s_setprio(0);

    const float scale2 = 0.18033688f; // 0.125 * log2(e)
    float rs = 0.f;
#pragma unroll
    for (int t = 0; t < KTN; ++t)
#pragma unroll
        for (int r = 0; r < 16; ++r) {
            float p = exp2f(fmaf(st[t][r], scale2, -24.0f));
            if (MASKED &&
                (kc + (kt0 + t) * 32 + (r & 3) + 8 * (r >> 2) + 4 * hi > qabs))
                p = 0.f;
            rs += p;
            st[t][r] = p;
        }
    rs += __shfl_xor(rs, 32);
    lrow += rs;

    __builtin_amdgcn_s_setprio(1);
#pragma unroll
    for (int t = 0; t < KTN; ++t)
#pragma unroll
        for (int s2 = 0; s2 < 2; ++s2) {
            const int bb = s2 * 8;
            unsigned c01 = cvtpk(st[t][bb + 0], st[t][bb + 1]);
            unsigned c23 = cvtpk(st[t][bb + 2], st[t][bb + 3]);
            unsigned c45 = cvtpk(st[t][bb + 4], st[t][bb + 5]);
            unsigned c67 = cvtpk(st[t][bb + 6], st[t][bb + 7]);
            asm("v_permlane32_swap_b32 %0, %1" : "+v"(c01), "+v"(c45));
            asm("v_permlane32_swap_b32 %0, %1" : "+v"(c23), "+v"(c67));
            int4v pw;
            pw[0] = (int)c01; pw[1] = (int)c23; pw[2] = (int)c45; pw[3] = (int)c67;
            const bf16x8 pa = __builtin_bit_cast(bf16x8, pw);
            const int ksg = (kt0 + t) * 2 + s2;
#pragma unroll
            for (int dblk = 0; dblk < 2; ++dblk) {
                const bf16x8 vb = *(const bf16x8*)(
                    Vsb + (dblk * 32 + ln31) * 64 + (((2 * ksg + hi) ^ sw) * 8));
                oacc[dblk] = __builtin_amdgcn_mfma_f32_32x32x16_bf16(
                    pa, vb, oacc[dblk], 0, 0, 0);
            }
        }
    __builtin_amdgcn_s_setprio(0);
}

__global__ __launch_bounds__(256, 4) void flash_attn(
    const bf16* __restrict__ QK, const bf16* __restrict__ VT,
    bf16* __restrict__ Op0, bf16* __restrict__ Op1, float* __restrict__ lpart)
{
    __shared__ bf16 Ks[2][64 * 64];
    __shared__ bf16 Vs[2][64 * 64];
    const int tid = threadIdx.x;
    const int ln = tid & 63, w = tid >> 6;       // 4 waves
    const int ln31 = ln & 31, hi = ln >> 5, sw = ln & 7;
    const int wg = blockIdx.x;                   // 0..1023
    const int g = wg & 31;                       // 2h+b -> same XCD across halves
    const int p = (wg >> 5) & 15;
    const int half = wg >> 9;                    // chunk parity class
    const int h = g >> 1, b = g & 1;
    const int q0A = p * 64, q0B = (31 - p) * 64;

    const bf16* Qb = QK + (size_t)b * TSEQ * QKROW + h * DKH;
    const bf16* Kb = Qb + 1024;
    const bf16* VTb = VT + (size_t)(b * NHEAD + h) * DKH * TSEQ;

    const int q1 = (w < 2 ? q0A : q0B) + (w & 1) * 32 + ln31;
    const int q2 = q0B + (w & 1) * 32 + ln31;

    bf16x8 qf1[4], qf2[4];
#pragma unroll
    for (int ks = 0; ks < 4; ++ks) {
        qf1[ks] = *(const bf16x8*)(Qb + (size_t)q1 * QKROW + ks * 16 + hi * 8);
        qf2[ks] = *(const bf16x8*)(Qb + (size_t)q2 * QKROW + ks * 16 + hi * 8);
    }
    WAIT_VM(0);   // qf complete before any DMA -> clean in-loop counts

    const int srow = (w & 1) * 32 + (ln >> 3);
    const int scol = ((ln & 7) ^ ((ln >> 3) & 7)) * 8;
    const bool stK = (w < 2);
    auto stage = [&](int buf, int kc) {
        if (stK) {
            const bf16* g2 = Kb + (size_t)(kc + srow) * QKROW + scol;
            bf16* s = &Ks[buf][(w & 1) * 32 * 64];
#pragma unroll
            for (int l = 0; l < 4; ++l)
                gll16(g2 + (size_t)(l * 8) * QKROW, s + l * 8 * 64);
        } else {
            const bf16* g2 = VTb + (size_t)srow * TSEQ + kc + scol;
            bf16* s = &Vs[buf][(w & 1) * 32 * 64];
#pragma unroll
            for (int l = 0; l < 4; ++l)
                gll16(g2 + (size_t)(l * 8) * TSEQ, s + l * 8 * 64);
        }
    };

    f32x16 oacc1[2] = {}, oacc2[2] = {};
    float l1 = 0.f, l2 = 0.f;

    const int nld = 32 - p;                      // full stream length (17..32)
    const int ni = (nld - half + 1) >> 1;        // my chunks: c = half + 2*i

    auto do_chunk = [&](int c, int buf) {
        const int kc = c * 64;
        const bf16* K = Ks[buf];
        const bf16* V = Vs[buf];
        if (c <= p) {            // phase1: full 64-key chunk, own tile
            if (w < 2 && c == p)
                tile_step<2, true >(0, kc, q1, K, V, qf1, oacc1, l1, ln31, hi, sw);
            else
                tile_step<2, false>(0, kc, q1, K, V, qf1, oacc1, l1, ln31, hi, sw);
        } else {                 // phase2: all waves on B, key-split
            const int kt0 = w >> 1;
            if (c == nld - 1)
                tile_step<1, true >(kt0, kc, q2, K, V, qf2, oacc2, l2, ln31, hi, sw);
            else
                tile_step<1, false>(kt0, kc, q2, K, V, qf2, oacc2, l2, ln31, hi, sw);
        }
    };

    stage(0, half * 64);
    WAIT_VM(0);
    __syncthreads();
    for (int i = 0; i < ni; ++i) {
        if (i + 1 < ni) stage((i + 1) & 1, (half + 2 * (i + 1)) * 64);
        do_chunk(half + 2 * i, i & 1);
        WAIT_VM(0);      // drain prefetch (overlapped with compute above)
        __syncthreads();
    }

    // ---- epilogue: combine phase2 partials (w0->w2, w1->w3) via LDS
    float* exO = (float*)&Ks[0][0];   // 2 x 32q x 64d f32 = 16KB (all of Ks)
    float* exL = (float*)&Vs[0][0];   // 2 x 32 f32
    if (w < 2) {
        float* dst = exO + w * 2048;
#pragma unroll
        for (int dblk = 0; dblk < 2; ++dblk)
#pragma unroll
            for (int r = 0; r < 16; ++r) {
                int q = (r & 3) + 8 * (r >> 2) + 4 * hi;
                dst[q * 64 + dblk * 32 + ln31] = oacc2[dblk][r];
            }
        if (ln < 32) exL[w * 32 + ln] = l2;
    }
    __syncthreads();

    f32x16 oat[2];
    float lt;
    int qs;
    if (w < 2) {
        oat[0] = oacc1[0]; oat[1] = oacc1[1];
        lt = l1;
        qs = q0A + (w & 1) * 32;
    } else {
        const float* src = exO + (w - 2) * 2048;
        lt = l1 + l2 + exL[(w - 2) * 32 + ln31];
#pragma unroll
        for (int dblk = 0; dblk < 2; ++dblk)
#pragma unroll
            for (int r = 0; r < 16; ++r) {
                int q = (r & 3) + 8 * (r >> 2) + 4 * hi;
                oat[dblk][r] = oacc1[dblk][r] + oacc2[dblk][r] +
                               src[q * 64 + dblk * 32 + ln31];
            }
        qs = q0B + (w & 1) * 32;
    }

    // ---- partial store (UNNORMALIZED; combine kernel divides)
    bf16* Ob = (b == 0 ? Op0 : Op1) + (size_t)half * (TSEQ * DMODEL);
    float* lp = lpart + half * 65536 + b * 32768 + h * 2048;
    if (hi == 0) lp[qs + ln31] = lt;   // lane r holds l of q-row qs+r
#pragma unroll
    for (int r = 0; r < 16; ++r) {
        const int crow = (r & 3) + 8 * (r >> 2) + 4 * hi;
        const int row = qs + crow;
#pragma unroll
        for (int dblk = 0; dblk < 2; ++dblk)
            Ob[(size_t)row * DMODEL + h * DKH + dblk * 32 + ln31] =
                (bf16)oat[dblk][r];
    }
}

// ---------------------------------------------------------------- combine
// O[b][row][hd] = (Op[b][half0] + Op[b][half1]) / (l0 + l1)
__global__ __launch_bounds__(256) void combine(
    const bf16* __restrict__ Op0, const bf16* __restrict__ Op1,
    const float* __restrict__ lpart, bf16* __restrict__ O)
{
    const int i = blockIdx.x * 256 + threadIdx.x;   // 0..524287
    const size_t e = (size_t)i * 8;
    const int b = (int)(e >> 21);
    const int rem = (int)(e & ((1u << 21) - 1));
    const int row = rem >> 10, hd = rem & 1023, h = hd >> 6;
    const bf16* base = (b == 0 ? Op0 : Op1);
    bf16x8 p0 = *(const bf16x8*)(base + rem);
    bf16x8 p1 = *(const bf16x8*)(base + (1u << 21) + rem);
    const float l = lpart[b * 32768 + h * 2048 + row] +
                    lpart[65536 + b * 32768 + h * 2048 + row];
    const float inv = 1.0f / l;
    bf16x8 o;
#pragma unroll
    for (int j = 0; j < 8; ++j)
        o[j] = (bf16)((float(p0[j]) + float(p1[j])) * inv);
    *(bf16x8*)(O + e) = o;
}

// ---------------------------------------------------------------- launch
// ws layout (56MB, all proven in-bounds):
//  0- 8MB : xb (QKV-GEMM input; DEAD after -> Opart batch0, 2 halves x 4MB)
//  8-24MB : QK [4096][2048] bf16 (Q,K only; V redirected to VT)
// 24-32MB : VT (8MB)
// 32-40MB : Opart batch1 (2 halves x 4MB)
// 40-48MB : wsBias (12KB, consumed by GEMM) then final O bf16 (combine writes)
// 48-56MB : WT (4 x 2MB); WQ dead after GEMM -> lpart (512KB) at WT+0
extern "C" void kernel_launch(void* const* d_in, const int* in_sizes, int n_in,
                              void* d_out, int out_size, void* d_ws, size_t ws_size,
                              hipStream_t stream)
{
    const float* x  = (const float*)d_in[0];
    const float* Wq = (const float*)d_in[2];
    const float* bq = (const float*)d_in[3];
    const float* Wk = (const float*)d_in[4];
    const float* bk = (const float*)d_in[5];
    const float* Wv = (const float*)d_in[6];
    const float* bv = (const float*)d_in[7];
    const float* Wo = (const float*)d_in[8];
    const float* bo = (const float*)d_in[9];

    char* ws = (char*)d_ws;
    bf16* xb    = (bf16*)(ws);                   // 8 MB (-> Opart b0 after GEMM)
    bf16* QK    = (bf16*)(ws + (8u  << 20));     // 16 MB
    bf16* VT    = (bf16*)(ws + (24u << 20));     // 8 MB
    bf16* Op1   = (bf16*)(ws + (32u << 20));     // 8 MB (Opart b1)
    bf16* O     = (bf16*)(ws + (40u << 20));     // 8 MB final O
    bf16* WT    = (bf16*)(ws + (48u << 20));     // 8 MB
    float* wsBias = (float*)O;                   // 12 KB, consumed before combine
    float* lpart  = (float*)WT;                  // 512 KB over dead WQ
    bf16* Op0   = xb;                            // aliases xb (dead post-GEMM)

    prep<<<PREP_GRID, 256, 0, stream>>>(x, Wq, Wk, Wv, Wo, bq, bk, bv,
                                        xb, WT, wsBias);

    gemm_bias_kernel<bf16, 2, true><<<768, 256, 0, stream>>>(
        xb, WT, wsBias, QK, QKROW, VT);

    flash_attn<<<1024, 256, 0, stream>>>(QK, VT, Op0, Op1, lpart);

    combine<<<2048, 256, 0, stream>>>(Op0, Op1, lpart, O);

    gemm_bias_kernel<float, 1, false><<<512, 256, 0, stream>>>(
        O, WT + 3u * (1u << 20), bo, (float*)d_out, DMODEL, nullptr);
}

// Round 13
// 213.658 us; speedup vs baseline: 1.2590x; 1.2590x over previous
//
#include <hip/hip_runtime.h>
#include <hip/hip_bf16.h>

typedef __bf16 bf16;
typedef __attribute__((ext_vector_type(8))) __bf16 bf16x8;
typedef __attribute__((ext_vector_type(4))) __bf16 bf16x4;
typedef __attribute__((ext_vector_type(4))) float f32x4;
typedef __attribute__((ext_vector_type(16))) float f32x16;
typedef __attribute__((ext_vector_type(4))) int int4v;

#define TSEQ 2048
#define DMODEL 1024
#define NHEAD 16
#define DKH 64
#define BATCH 2
#define NQKV 3072

// async global->LDS, 16B per lane; LDS dest = wave-uniform base + lane*16
typedef __attribute__((address_space(1))) const void gv_t;
typedef __attribute__((address_space(3))) void sv_t;
__device__ __forceinline__ void gll16(const bf16* g, bf16* s) {
    __builtin_amdgcn_global_load_lds((gv_t*)g, (sv_t*)s, 16, 0, 0);
}
// counted vmcnt wait (lgkmcnt=15, expcnt=7 untouched). __syncthreads does NOT
// drain DMA vmcnt on this toolchain -> explicit wait required.
#define WAIT_VM(n) __builtin_amdgcn_s_waitcnt(0x0F70 | (n))

// v_cvt_pk_bf16_f32: D.lo = bf16(s0), D.hi = bf16(s1)
__device__ __forceinline__ unsigned cvtpk(float lo, float hi) {
    unsigned d;
    asm("v_cvt_pk_bf16_f32 %0, %1, %2" : "=v"(d) : "v"(lo), "v"(hi));
    return d;
}

// ------------------------------------------------------- fused prep kernel
#define PREP_CONV 4096   // NX / (256*4)
#define PREP_TW   4096
#define PREP_GRID (PREP_CONV + PREP_TW + 12)
__global__ __launch_bounds__(256) void prep(
    const float* __restrict__ x,
    const float* __restrict__ Wq, const float* __restrict__ Wk,
    const float* __restrict__ Wv, const float* __restrict__ Wo,
    const float* __restrict__ bq, const float* __restrict__ bk,
    const float* __restrict__ bv,
    bf16* __restrict__ xb, bf16* __restrict__ WT, float* __restrict__ biasO)
{
    __shared__ float t[32][33];
    int bid = blockIdx.x;
    const int tid = threadIdx.x;
    if (bid < PREP_CONV) {                       // ---- convert
        int i = (bid * 256 + tid) * 4;
        f32x4 v = *(const f32x4*)(x + i);
        bf16x4 o;
#pragma unroll
        for (int j = 0; j < 4; ++j) o[j] = (bf16)v[j];
        *(bf16x4*)(xb + i) = o;
        return;
    }
    bid -= PREP_CONV;
    if (bid < PREP_TW) {                         // ---- transpose W (32x32 tile)
        int z = bid >> 10;
        int by = ((bid >> 5) & 31) * 32, bx = (bid & 31) * 32;
        const float* W = z == 0 ? Wq : z == 1 ? Wk : z == 2 ? Wv : Wo;
        bf16* T = WT + (size_t)z * DMODEL * DMODEL;
        int tx = tid & 31, ty = tid >> 5;
#pragma unroll
        for (int i = 0; i < 4; ++i)
            t[ty + i * 8][tx] = W[(size_t)(by + ty + i * 8) * DMODEL + bx + tx];
        __syncthreads();
#pragma unroll
        for (int i = 0; i < 4; ++i)
            T[(size_t)(bx + ty + i * 8) * DMODEL + by + tx] = (bf16)t[tx][ty + i * 8];
        return;
    }
    bid -= PREP_TW;
    int i = bid * 256 + tid;                     // ---- bias concat, 0..3071
    float v = i < 1024 ? bq[i] : i < 2048 ? bk[i - 1024] : bv[i - 2048];
    biasO[i] = v;
}

// ---------------------------------------------------------------- GEMM + bias
// (r11 body, proven) BK=64, 2-buffer, XOR-swizzled LDS tiles, XCD-chunked
// mapping. FUSE_VT: n0>=2048 writes V-part transposed to VT.
template <typename OutT, int NW_N, bool FUSE_VT>
__global__ __launch_bounds__(256) void gemm_bias_kernel(
    const bf16* __restrict__ A, const bf16* __restrict__ BT,
    const float* __restrict__ bias, OutT* __restrict__ C, int ldc,
    bf16* __restrict__ VT)
{
    constexpr int BN    = NW_N * 64;
    constexpr int MW    = 4 / NW_N;
    constexpr int WROWS = 128 / MW;
    constexpr int FM    = WROWS / 16;
    constexpr int BK    = 64;
    constexpr int ASZ   = 128 * BK;
    constexpr int BSZ   = BN * BK;
    constexpr int BNP   = BN + 4;
    constexpr int TST   = 136;
    constexpr int EPI   = sizeof(OutT) == 2 ? (FUSE_VT ? 128 * TST : 128 * BN)
                                            : 64 * BNP * 2;
    constexpr int STG   = 2 * ASZ + 2 * BSZ;
    constexpr int SMEM  = STG > EPI ? STG : EPI;
    __shared__ bf16 smem[SMEM];
    bf16* As0 = smem;
    bf16* Bs0 = smem + 2 * ASZ;

    const int tid = threadIdx.x;
    const int ln = tid & 63, wave = tid >> 6;
    const int wm = NW_N == 2 ? (wave >> 1) : wave;
    const int wn = NW_N == 2 ? (wave & 1) : 0;
    const int lr = ln & 15, quad = ln >> 4;

    constexpr int NBX = (NW_N == 2) ? 24 : 16;
    constexpr int CH  = (NW_N == 2) ? 96 : 64;
    const int wg  = blockIdx.x;
    const int lin = (wg & 7) * CH + (wg >> 3);
    const int m0  = (lin / NBX) * 128, n0 = (lin % NBX) * BN;

    f32x4 acc[FM][4] = {};

    const int srow = ln >> 3;
    const int scol = ((ln & 7) ^ srow) * 8;
    const bf16* Ag = A + (size_t)(m0 + wave * 32 + srow) * DMODEL + scol;
    const bf16* Bg = BT + (size_t)(n0 + (NW_N == 2 ? wave * 32 : wave * 16) + srow) * DMODEL + scol;

    auto stage = [&](int buf, int kk) {
        bf16* AsW = As0 + buf * ASZ + wave * (32 * BK);
#pragma unroll
        for (int l = 0; l < 4; ++l)
            gll16(Ag + (size_t)(l * 8) * DMODEL + kk, AsW + l * 8 * BK);
        if constexpr (NW_N == 2) {
            bf16* BsW = Bs0 + buf * BSZ + wave * (32 * BK);
#pragma unroll
            for (int l = 0; l < 4; ++l)
                gll16(Bg + (size_t)(l * 8) * DMODEL + kk, BsW + l * 8 * BK);
        } else {
            bf16* BsW = Bs0 + buf * BSZ + wave * (16 * BK);
#pragma unroll
            for (int l = 0; l < 2; ++l)
                gll16(Bg + (size_t)(l * 8) * DMODEL + kk, BsW + l * 8 * BK);
        }
    };

    constexpr int NT = DMODEL / BK;
    stage(0, 0);
    WAIT_VM(0);
    __syncthreads();
    const int swr = lr & 7;
    for (int kt = 0; kt < NT; ++kt) {
        if (kt + 1 < NT) stage((kt + 1) & 1, (kt + 1) * BK);
        const bf16* AsB = As0 + (kt & 1) * ASZ;
        const bf16* BsB = Bs0 + (kt & 1) * BSZ;
#pragma unroll
        for (int k2 = 0; k2 < 2; ++k2) {
            bf16x8 af[FM], bfr[4];
#pragma unroll
            for (int i = 0; i < FM; ++i)
                af[i] = *(const bf16x8*)(AsB + (wm * WROWS + i * 16 + lr) * BK +
                                         (((k2 * 4 + quad) ^ swr) * 8));
#pragma unroll
            for (int j = 0; j < 4; ++j)
                bfr[j] = *(const bf16x8*)(BsB + (wn * 64 + j * 16 + lr) * BK +
                                          (((k2 * 4 + quad) ^ swr) * 8));
#pragma unroll
            for (int i = 0; i < FM; ++i)
#pragma unroll
                for (int j = 0; j < 4; ++j)
                    acc[i][j] = __builtin_amdgcn_mfma_f32_16x16x32_bf16(
                        af[i], bfr[j], acc[i][j], 0, 0, 0);
        }
        WAIT_VM(0);
        __syncthreads();
    }

    if constexpr (sizeof(OutT) == 2) {
        if (FUSE_VT && n0 >= 2048) {
            bf16* Cs = smem;
#pragma unroll
            for (int j = 0; j < 4; ++j) {
                int nl = wn * 64 + j * 16 + lr;
                float bv = bias[n0 + nl];
#pragma unroll
                for (int i = 0; i < FM; ++i) {
                    int ml = wm * WROWS + i * 16 + quad * 4;
#pragma unroll
                    for (int r = 0; r < 4; ++r)
                        Cs[nl * TST + ml + r] = (bf16)(acc[i][j][r] + bv);
                }
            }
            __syncthreads();
            const int bb = m0 >> 11;
            const int tloc = m0 & 2047;
#pragma unroll
            for (int pp = 0; pp < 8; ++pp) {
                int dl = pp * 16 + (tid >> 4);
                int t0 = (tid & 15) * 8;
                bf16x8 v = *(const bf16x8*)(Cs + dl * TST + t0);
                *(bf16x8*)(VT + (size_t)(bb * 1024 + (n0 - 2048) + dl) * TSEQ +
                           tloc + t0) = v;
            }
            return;
        }
        bf16* Cs = smem;
#pragma unroll
        for (int j = 0; j < 4; ++j) {
            int nl = wn * 64 + j * 16 + lr;
            float bv = bias[n0 + nl];
#pragma unroll
            for (int i = 0; i < FM; ++i) {
                int ml = wm * WROWS + i * 16 + quad * 4;
#pragma unroll
                for (int r = 0; r < 4; ++r)
                    Cs[(ml + r) * BN + nl] = (bf16)(acc[i][j][r] + bv);
            }
        }
        __syncthreads();
        constexpr int LPR = BN / 8;
        constexpr int RPP = 256 / LPR;
        const int rr = tid / LPR, cc = (tid % LPR) * 8;
#pragma unroll
        for (int pp = 0; pp < 128 / RPP; ++pp) {
            int row = pp * RPP + rr;
            *(bf16x8*)(C + (size_t)(m0 + row) * ldc + n0 + cc) =
                *(const bf16x8*)(Cs + row * BN + cc);
        }
    } else {
        float* Cf = (float*)smem;
#pragma unroll
        for (int half = 0; half < 2; ++half) {
            if (((wm * WROWS) >> 6) == half) {
#pragma unroll
                for (int j = 0; j < 4; ++j) {
                    int nl = wn * 64 + j * 16 + lr;
                    float bv = bias[n0 + nl];
#pragma unroll
                    for (int i = 0; i < FM; ++i) {
                        int ml = wm * WROWS + i * 16 + quad * 4 - half * 64;
#pragma unroll
                        for (int r = 0; r < 4; ++r)
                            Cf[(ml + r) * BNP + nl] = acc[i][j][r] + bv;
                    }
                }
            }
            __syncthreads();
            constexpr int LPR = BN / 4;
            constexpr int RPP = 256 / LPR;
            const int rr = tid / LPR, cc = (tid % LPR) * 4;
#pragma unroll
            for (int pp = 0; pp < 64 / RPP; ++pp) {
                int row = pp * RPP + rr;
                *(f32x4*)(C + (size_t)(m0 + half * 64 + row) * ldc + n0 + cc) =
                    *(const f32x4*)(Cf + row * BNP + cc);
            }
            __syncthreads();
        }
    }
}

// ---------------------------------------------------------------- flash attn
// 1024 blocks x 128 threads (2 waves): pair (P, 63-P) of 32-ROW q-tiles over
// one shared K/V stream (nld = (63-P)/2+1 in 17..32; uniform 2-wave work per
// chunk). vs r11's 512x256: same total waves, but 4-5 INDEPENDENT blocks/CU
// (32KB LDS) instead of 2 lock-stepped ones -> stalls overlap across blocks,
// barriers sync only 2 waves, finer tail granularity. No split-K, no partial
// writes (r12's 10x HBM-traffic poison reverted). Micro-structure (32x32
// swapped-QK^T, in-register softmax, cvt_pk+permlane P path, XOR swizzle,
// fixed-max M=24 exp2 softmax) carried verbatim from r7/r11.
template <int KTN, bool MASKED>
__device__ __forceinline__ void tile_step(
    int kt0, int kc, int qabs,
    const bf16* __restrict__ Ksb, const bf16* __restrict__ Vsb,
    const bf16x8 qf[4], f32x16 oacc[2], float& lrow,
    int ln31, int hi, int sw)
{
    f32x16 st[KTN] = {};
    __builtin_amdgcn_s_setprio(1);
#pragma unroll
    for (int t = 0; t < KTN; ++t)
#pragma unroll
        for (int ks = 0; ks < 4; ++ks) {
            const bf16x8 ka = *(const bf16x8*)(
                Ksb + (ln31 + (kt0 + t) * 32) * 64 + (((2 * ks + hi) ^ sw) * 8));
            st[t] = __builtin_amdgcn_mfma_f32_32x32x16_bf16(ka, qf[ks], st[t], 0, 0, 0);
        }
    __builtin_amdgcn_s_setprio(0);

    const float scale2 = 0.18033688f; // 0.125 * log2(e)
    float rs = 0.f;
#pragma unroll
    for (int t = 0; t < KTN; ++t)
#pragma unroll
        for (int r = 0; r < 16; ++r) {
            float p = exp2f(fmaf(st[t][r], scale2, -24.0f));
            if (MASKED &&
                (kc + (kt0 + t) * 32 + (r & 3) + 8 * (r >> 2) + 4 * hi > qabs))
                p = 0.f;
            rs += p;
            st[t][r] = p;
        }
    rs += __shfl_xor(rs, 32);
    lrow += rs;

    __builtin_amdgcn_s_setprio(1);
#pragma unroll
    for (int t = 0; t < KTN; ++t)
#pragma unroll
        for (int s2 = 0; s2 < 2; ++s2) {
            const int bb = s2 * 8;
            unsigned c01 = cvtpk(st[t][bb + 0], st[t][bb + 1]);
            unsigned c23 = cvtpk(st[t][bb + 2], st[t][bb + 3]);
            unsigned c45 = cvtpk(st[t][bb + 4], st[t][bb + 5]);
            unsigned c67 = cvtpk(st[t][bb + 6], st[t][bb + 7]);
            asm("v_permlane32_swap_b32 %0, %1" : "+v"(c01), "+v"(c45));
            asm("v_permlane32_swap_b32 %0, %1" : "+v"(c23), "+v"(c67));
            int4v pw;
            pw[0] = (int)c01; pw[1] = (int)c23; pw[2] = (int)c45; pw[3] = (int)c67;
            const bf16x8 pa = __builtin_bit_cast(bf16x8, pw);
            const int ksg = (kt0 + t) * 2 + s2;
#pragma unroll
            for (int dblk = 0; dblk < 2; ++dblk) {
                const bf16x8 vb = *(const bf16x8*)(
                    Vsb + (dblk * 32 + ln31) * 64 + (((2 * ksg + hi) ^ sw) * 8));
                oacc[dblk] = __builtin_amdgcn_mfma_f32_32x32x16_bf16(
                    pa, vb, oacc[dblk], 0, 0, 0);
            }
        }
    __builtin_amdgcn_s_setprio(0);
}

__global__ __launch_bounds__(128, 2) void flash_attn(
    const bf16* __restrict__ QKV, const bf16* __restrict__ VT,
    bf16* __restrict__ O)
{
    __shared__ bf16 Ks[2][64 * 64];   // 16 KB
    __shared__ bf16 Vs[2][64 * 64];   // 16 KB
    const int tid = threadIdx.x;
    const int ln = tid & 63, w = tid >> 6;       // 2 waves
    const int ln31 = ln & 31, hi = ln >> 5, sw = ln & 7;
    const int wg = blockIdx.x;                   // 0..1023
    const int g = wg & 31, P = wg >> 5;          // g = 2h+b -> fixed XCD
    const int h = g >> 1, b = g & 1;
    const int cA = P >> 1;                       // A's diagonal chunk
    const int nld = ((63 - P) >> 1) + 1;         // stream length (17..32)
    const int q0A = P * 32, q0B = (63 - P) * 32;

    const bf16* Qb = QKV + (size_t)b * TSEQ * NQKV + h * DKH;
    const bf16* Kb = Qb + 1024;
    const bf16* VTb = VT + (size_t)(b * NHEAD + h) * DKH * TSEQ;

    // w0 owns A-rows in phase1; w1 owns B-rows. Phase2: both on B, key-split.
    const int q1 = (w == 0 ? q0A : q0B) + ln31;
    const int q2 = q0B + ln31;

    bf16x8 qf1[4], qf2[4];
#pragma unroll
    for (int ks = 0; ks < 4; ++ks) {
        qf1[ks] = *(const bf16x8*)(Qb + (size_t)q1 * NQKV + ks * 16 + hi * 8);
        qf2[ks] = *(const bf16x8*)(Qb + (size_t)q2 * NQKV + ks * 16 + hi * 8);
    }
    WAIT_VM(0);   // qf complete before any DMA -> clean in-loop counts

    // staging: w0 -> all 64 K rows (8 gll16), w1 -> all 64 V rows.
    const int srow = ln >> 3;                    // 0..7
    const int scol = ((ln & 7) ^ srow) * 8;      // XOR swizzle by row&7
    auto stage = [&](int buf, int kc) {
        if (w == 0) {
            const bf16* g2 = Kb + (size_t)(kc + srow) * NQKV + scol;
            bf16* s = &Ks[buf][0];
#pragma unroll
            for (int l = 0; l < 8; ++l)
                gll16(g2 + (size_t)(l * 8) * NQKV, s + l * 8 * 64);
        } else {
            const bf16* g2 = VTb + (size_t)srow * TSEQ + kc + scol;
            bf16* s = &Vs[buf][0];
#pragma unroll
            for (int l = 0; l < 8; ++l)
                gll16(g2 + (size_t)(l * 8) * TSEQ, s + l * 8 * 64);
        }
    };

    f32x16 oacc1[2] = {}, oacc2[2] = {};
    float l1 = 0.f, l2 = 0.f;

    stage(0, 0);
    WAIT_VM(0);
    __syncthreads();
    for (int c = 0; c < nld; ++c) {
        if (c + 1 < nld) stage((c + 1) & 1, (c + 1) * 64); // async prefetch
        const int kc = c * 64;
        const bf16* K = Ks[c & 1];
        const bf16* V = Vs[c & 1];
        if (c <= cA) {           // phase1: full 64-key chunk, own tile
            if (w == 0 && c == cA)
                tile_step<2, true >(0, kc, q1, K, V, qf1, oacc1, l1, ln31, hi, sw);
            else
                tile_step<2, false>(0, kc, q1, K, V, qf1, oacc1, l1, ln31, hi, sw);
        } else {                 // phase2: both waves on B, key-split (kt0=w)
            if (c == nld - 1)
                tile_step<1, true >(w, kc, q2, K, V, qf2, oacc2, l2, ln31, hi, sw);
            else
                tile_step<1, false>(w, kc, q2, K, V, qf2, oacc2, l2, ln31, hi, sw);
        }
        WAIT_VM(0);      // drain own prefetch (overlapped with compute above)
        __syncthreads();
    }

    // ---- epilogue: w0's B-phase2 partial -> LDS; w1 combines
    float* exO = (float*)&Ks[0][0];   // 32q x 64d f32 = 8KB
    float* exL = (float*)&Vs[0][0];   // 32 f32
    if (w == 0) {
#pragma unroll
        for (int dblk = 0; dblk < 2; ++dblk)
#pragma unroll
            for (int r = 0; r < 16; ++r) {
                int q = (r & 3) + 8 * (r >> 2) + 4 * hi;
                exO[q * 64 + dblk * 32 + ln31] = oacc2[dblk][r];
            }
        if (ln < 32) exL[ln] = l2;
    }
    __syncthreads();

    f32x16 oat[2];
    float lt;
    int qs;
    if (w == 0) {
        oat[0] = oacc1[0]; oat[1] = oacc1[1];
        lt = l1;
        qs = q0A;
    } else {
        lt = l1 + l2 + exL[ln31];
#pragma unroll
        for (int dblk = 0; dblk < 2; ++dblk)
#pragma unroll
            for (int r = 0; r < 16; ++r) {
                int q = (r & 3) + 8 * (r >> 2) + 4 * hi;
                oat[dblk][r] = oacc1[dblk][r] + oacc2[dblk][r] +
                               exO[q * 64 + dblk * 32 + ln31];
            }
        qs = q0B;
    }

#pragma unroll
    for (int r = 0; r < 16; ++r) {
        const int crow = (r & 3) + 8 * (r >> 2) + 4 * hi;
        const float inv = 1.0f / __shfl(lt, crow);
        const int row = qs + crow;
#pragma unroll
        for (int dblk = 0; dblk < 2; ++dblk)
            O[(size_t)(b * TSEQ + row) * DMODEL + h * DKH + dblk * 32 + ln31] =
                (bf16)(oat[dblk][r] * inv);
    }
}

// ---------------------------------------------------------------- launch
extern "C" void kernel_launch(void* const* d_in, const int* in_sizes, int n_in,
                              void* d_out, int out_size, void* d_ws, size_t ws_size,
                              hipStream_t stream)
{
    const float* x  = (const float*)d_in[0];
    const float* Wq = (const float*)d_in[2];
    const float* bq = (const float*)d_in[3];
    const float* Wk = (const float*)d_in[4];
    const float* bk = (const float*)d_in[5];
    const float* Wv = (const float*)d_in[6];
    const float* bv = (const float*)d_in[7];
    const float* Wo = (const float*)d_in[8];
    const float* bo = (const float*)d_in[9];

    char* ws = (char*)d_ws;
    bf16* xb   = (bf16*)(ws);                   // 8 MB
    bf16* QKV  = (bf16*)(ws + (8u  << 20));     // 24 MB [4096][3072] (V third unused)
    bf16* VT   = (bf16*)(ws + (32u << 20));     // 8 MB, written by QKV-GEMM V blocks
    bf16* O    = (bf16*)(ws + (40u << 20));     // 8 MB
    bf16* WT   = (bf16*)(ws + (48u << 20));     // 8 MB
    float* wsBias = (float*)O;                  // 12 KB, consumed before flash writes O

    prep<<<PREP_GRID, 256, 0, stream>>>(x, Wq, Wk, Wv, Wo, bq, bk, bv,
                                        xb, WT, wsBias);

    gemm_bias_kernel<bf16, 2, true><<<768, 256, 0, stream>>>(
        xb, WT, wsBias, QKV, NQKV, VT);

    flash_attn<<<1024, 128, 0, stream>>>(QKV, VT, O);

    gemm_bias_kernel<float, 1, false><<<512, 256, 0, stream>>>(
        O, WT + 3u * (1u << 20), bo, (float*)d_out, DMODEL, nullptr);
}

// Round 14
// 197.256 us; speedup vs baseline: 1.3637x; 1.0832x over previous
//
#include <hip/hip_runtime.h>
#include <hip/hip_bf16.h>

typedef __bf16 bf16;
typedef __attribute__((ext_vector_type(8))) __bf16 bf16x8;
typedef __attribute__((ext_vector_type(4))) __bf16 bf16x4;
typedef __attribute__((ext_vector_type(4))) float f32x4;
typedef __attribute__((ext_vector_type(16))) float f32x16;
typedef __attribute__((ext_vector_type(4))) int int4v;

#define TSEQ 2048
#define DMODEL 1024
#define NHEAD 16
#define DKH 64
#define BATCH 2
#define NQKV 3072

// async global->LDS, 16B per lane; LDS dest = wave-uniform base + lane*16
typedef __attribute__((address_space(1))) const void gv_t;
typedef __attribute__((address_space(3))) void sv_t;
__device__ __forceinline__ void gll16(const bf16* g, bf16* s) {
    __builtin_amdgcn_global_load_lds((gv_t*)g, (sv_t*)s, 16, 0, 0);
}
// counted vmcnt wait (lgkmcnt=15, expcnt=7 untouched). __syncthreads does NOT
// drain DMA vmcnt on this toolchain -> explicit wait required.
#define WAIT_VM(n) __builtin_amdgcn_s_waitcnt(0x0F70 | (n))

// v_cvt_pk_bf16_f32: D.lo = bf16(s0), D.hi = bf16(s1)
__device__ __forceinline__ unsigned cvtpk(float lo, float hi) {
    unsigned d;
    asm("v_cvt_pk_bf16_f32 %0, %1, %2" : "=v"(d) : "v"(lo), "v"(hi));
    return d;
}

// ------------------------------------------------------- fused prep kernel
#define PREP_CONV 4096   // NX / (256*4)
#define PREP_TW   4096
#define PREP_GRID (PREP_CONV + PREP_TW + 12)
__global__ __launch_bounds__(256) void prep(
    const float* __restrict__ x,
    const float* __restrict__ Wq, const float* __restrict__ Wk,
    const float* __restrict__ Wv, const float* __restrict__ Wo,
    const float* __restrict__ bq, const float* __restrict__ bk,
    const float* __restrict__ bv,
    bf16* __restrict__ xb, bf16* __restrict__ WT, float* __restrict__ biasO)
{
    __shared__ float t[32][33];
    int bid = blockIdx.x;
    const int tid = threadIdx.x;
    if (bid < PREP_CONV) {                       // ---- convert
        int i = (bid * 256 + tid) * 4;
        f32x4 v = *(const f32x4*)(x + i);
        bf16x4 o;
#pragma unroll
        for (int j = 0; j < 4; ++j) o[j] = (bf16)v[j];
        *(bf16x4*)(xb + i) = o;
        return;
    }
    bid -= PREP_CONV;
    if (bid < PREP_TW) {                         // ---- transpose W (32x32 tile)
        int z = bid >> 10;
        int by = ((bid >> 5) & 31) * 32, bx = (bid & 31) * 32;
        const float* W = z == 0 ? Wq : z == 1 ? Wk : z == 2 ? Wv : Wo;
        bf16* T = WT + (size_t)z * DMODEL * DMODEL;
        int tx = tid & 31, ty = tid >> 5;
#pragma unroll
        for (int i = 0; i < 4; ++i)
            t[ty + i * 8][tx] = W[(size_t)(by + ty + i * 8) * DMODEL + bx + tx];
        __syncthreads();
#pragma unroll
        for (int i = 0; i < 4; ++i)
            T[(size_t)(bx + ty + i * 8) * DMODEL + by + tx] = (bf16)t[tx][ty + i * 8];
        return;
    }
    bid -= PREP_TW;
    int i = bid * 256 + tid;                     // ---- bias concat, 0..3071
    float v = i < 1024 ? bq[i] : i < 2048 ? bk[i - 1024] : bv[i - 2048];
    biasO[i] = v;
}

// ---------------------------------------------------------------- GEMM + bias
// (r11 body, proven) BK=64, 2-buffer, XOR-swizzled LDS tiles, XCD-chunked
// mapping. FUSE_VT: n0>=2048 writes V-part transposed to VT.
template <typename OutT, int NW_N, bool FUSE_VT>
__global__ __launch_bounds__(256) void gemm_bias_kernel(
    const bf16* __restrict__ A, const bf16* __restrict__ BT,
    const float* __restrict__ bias, OutT* __restrict__ C, int ldc,
    bf16* __restrict__ VT)
{
    constexpr int BN    = NW_N * 64;
    constexpr int MW    = 4 / NW_N;
    constexpr int WROWS = 128 / MW;
    constexpr int FM    = WROWS / 16;
    constexpr int BK    = 64;
    constexpr int ASZ   = 128 * BK;
    constexpr int BSZ   = BN * BK;
    constexpr int BNP   = BN + 4;
    constexpr int TST   = 136;
    constexpr int EPI   = sizeof(OutT) == 2 ? (FUSE_VT ? 128 * TST : 128 * BN)
                                            : 64 * BNP * 2;
    constexpr int STG   = 2 * ASZ + 2 * BSZ;
    constexpr int SMEM  = STG > EPI ? STG : EPI;
    __shared__ bf16 smem[SMEM];
    bf16* As0 = smem;
    bf16* Bs0 = smem + 2 * ASZ;

    const int tid = threadIdx.x;
    const int ln = tid & 63, wave = tid >> 6;
    const int wm = NW_N == 2 ? (wave >> 1) : wave;
    const int wn = NW_N == 2 ? (wave & 1) : 0;
    const int lr = ln & 15, quad = ln >> 4;

    constexpr int NBX = (NW_N == 2) ? 24 : 16;
    constexpr int CH  = (NW_N == 2) ? 96 : 64;
    const int wg  = blockIdx.x;
    const int lin = (wg & 7) * CH + (wg >> 3);
    const int m0  = (lin / NBX) * 128, n0 = (lin % NBX) * BN;

    f32x4 acc[FM][4] = {};

    const int srow = ln >> 3;
    const int scol = ((ln & 7) ^ srow) * 8;
    const bf16* Ag = A + (size_t)(m0 + wave * 32 + srow) * DMODEL + scol;
    const bf16* Bg = BT + (size_t)(n0 + (NW_N == 2 ? wave * 32 : wave * 16) + srow) * DMODEL + scol;

    auto stage = [&](int buf, int kk) {
        bf16* AsW = As0 + buf * ASZ + wave * (32 * BK);
#pragma unroll
        for (int l = 0; l < 4; ++l)
            gll16(Ag + (size_t)(l * 8) * DMODEL + kk, AsW + l * 8 * BK);
        if constexpr (NW_N == 2) {
            bf16* BsW = Bs0 + buf * BSZ + wave * (32 * BK);
#pragma unroll
            for (int l = 0; l < 4; ++l)
                gll16(Bg + (size_t)(l * 8) * DMODEL + kk, BsW + l * 8 * BK);
        } else {
            bf16* BsW = Bs0 + buf * BSZ + wave * (16 * BK);
#pragma unroll
            for (int l = 0; l < 2; ++l)
                gll16(Bg + (size_t)(l * 8) * DMODEL + kk, BsW + l * 8 * BK);
        }
    };

    constexpr int NT = DMODEL / BK;
    stage(0, 0);
    WAIT_VM(0);
    __syncthreads();
    const int swr = lr & 7;
    for (int kt = 0; kt < NT; ++kt) {
        if (kt + 1 < NT) stage((kt + 1) & 1, (kt + 1) * BK);
        const bf16* AsB = As0 + (kt & 1) * ASZ;
        const bf16* BsB = Bs0 + (kt & 1) * BSZ;
#pragma unroll
        for (int k2 = 0; k2 < 2; ++k2) {
            bf16x8 af[FM], bfr[4];
#pragma unroll
            for (int i = 0; i < FM; ++i)
                af[i] = *(const bf16x8*)(AsB + (wm * WROWS + i * 16 + lr) * BK +
                                         (((k2 * 4 + quad) ^ swr) * 8));
#pragma unroll
            for (int j = 0; j < 4; ++j)
                bfr[j] = *(const bf16x8*)(BsB + (wn * 64 + j * 16 + lr) * BK +
                                          (((k2 * 4 + quad) ^ swr) * 8));
#pragma unroll
            for (int i = 0; i < FM; ++i)
#pragma unroll
                for (int j = 0; j < 4; ++j)
                    acc[i][j] = __builtin_amdgcn_mfma_f32_16x16x32_bf16(
                        af[i], bfr[j], acc[i][j], 0, 0, 0);
        }
        WAIT_VM(0);
        __syncthreads();
    }

    if constexpr (sizeof(OutT) == 2) {
        if (FUSE_VT && n0 >= 2048) {
            bf16* Cs = smem;
#pragma unroll
            for (int j = 0; j < 4; ++j) {
                int nl = wn * 64 + j * 16 + lr;
                float bv = bias[n0 + nl];
#pragma unroll
                for (int i = 0; i < FM; ++i) {
                    int ml = wm * WROWS + i * 16 + quad * 4;
#pragma unroll
                    for (int r = 0; r < 4; ++r)
                        Cs[nl * TST + ml + r] = (bf16)(acc[i][j][r] + bv);
                }
            }
            __syncthreads();
            const int bb = m0 >> 11;
            const int tloc = m0 & 2047;
#pragma unroll
            for (int pp = 0; pp < 8; ++pp) {
                int dl = pp * 16 + (tid >> 4);
                int t0 = (tid & 15) * 8;
                bf16x8 v = *(const bf16x8*)(Cs + dl * TST + t0);
                *(bf16x8*)(VT + (size_t)(bb * 1024 + (n0 - 2048) + dl) * TSEQ +
                           tloc + t0) = v;
            }
            return;
        }
        bf16* Cs = smem;
#pragma unroll
        for (int j = 0; j < 4; ++j) {
            int nl = wn * 64 + j * 16 + lr;
            float bv = bias[n0 + nl];
#pragma unroll
            for (int i = 0; i < FM; ++i) {
                int ml = wm * WROWS + i * 16 + quad * 4;
#pragma unroll
                for (int r = 0; r < 4; ++r)
                    Cs[(ml + r) * BN + nl] = (bf16)(acc[i][j][r] + bv);
            }
        }
        __syncthreads();
        constexpr int LPR = BN / 8;
        constexpr int RPP = 256 / LPR;
        const int rr = tid / LPR, cc = (tid % LPR) * 8;
#pragma unroll
        for (int pp = 0; pp < 128 / RPP; ++pp) {
            int row = pp * RPP + rr;
            *(bf16x8*)(C + (size_t)(m0 + row) * ldc + n0 + cc) =
                *(const bf16x8*)(Cs + row * BN + cc);
        }
    } else {
        float* Cf = (float*)smem;
#pragma unroll
        for (int half = 0; half < 2; ++half) {
            if (((wm * WROWS) >> 6) == half) {
#pragma unroll
                for (int j = 0; j < 4; ++j) {
                    int nl = wn * 64 + j * 16 + lr;
                    float bv = bias[n0 + nl];
#pragma unroll
                    for (int i = 0; i < FM; ++i) {
                        int ml = wm * WROWS + i * 16 + quad * 4 - half * 64;
#pragma unroll
                        for (int r = 0; r < 4; ++r)
                            Cf[(ml + r) * BNP + nl] = acc[i][j][r] + bv;
                    }
                }
            }
            __syncthreads();
            constexpr int LPR = BN / 4;
            constexpr int RPP = 256 / LPR;
            const int rr = tid / LPR, cc = (tid % LPR) * 4;
#pragma unroll
            for (int pp = 0; pp < 64 / RPP; ++pp) {
                int row = pp * RPP + rr;
                *(f32x4*)(C + (size_t)(m0 + half * 64 + row) * ldc + n0 + cc) =
                    *(const f32x4*)(Cf + row * BNP + cc);
            }
            __syncthreads();
        }
    }
}

// ---------------------------------------------------------------- flash attn
// (r7/r11-proven, best-known: 45.3us) 32x32x16 swapped-QK^T, softmax fully
// in-register (fixed-max M=24 exp2 domain; shift-invariant), P->A-frag via
// cvt_pk + v_permlane32_swap_b32, paired tiles A=p/B=31-p sharing one K/V
// stream (uniform work), 2 chunks per iteration over 4 LDS buffers with the
// wait-before-issue counted-vmcnt shell.
template <int KTN, bool MASKED>
__device__ __forceinline__ void tile_step(
    int kt0, int kc, int qabs,
    const bf16* __restrict__ Ksb, const bf16* __restrict__ Vsb,
    const bf16x8 qf[4], f32x16 oacc[2], float& lrow,
    int ln31, int hi, int sw)
{
    f32x16 st[KTN] = {};
    __builtin_amdgcn_s_setprio(1);
#pragma unroll
    for (int t = 0; t < KTN; ++t)
#pragma unroll
        for (int ks = 0; ks < 4; ++ks) {
            const bf16x8 ka = *(const bf16x8*)(
                Ksb + (ln31 + (kt0 + t) * 32) * 64 + (((2 * ks + hi) ^ sw) * 8));
            st[t] = __builtin_amdgcn_mfma_f32_32x32x16_bf16(ka, qf[ks], st[t], 0, 0, 0);
        }
    __builtin_amdgcn_s_setprio(0);

    const float scale2 = 0.18033688f; // 0.125 * log2(e)
    float rs = 0.f;
#pragma unroll
    for (int t = 0; t < KTN; ++t)
#pragma unroll
        for (int r = 0; r < 16; ++r) {
            float p = exp2f(fmaf(st[t][r], scale2, -24.0f));
            if (MASKED &&
                (kc + (kt0 + t) * 32 + (r & 3) + 8 * (r >> 2) + 4 * hi > qabs))
                p = 0.f;
            rs += p;
            st[t][r] = p;
        }
    rs += __shfl_xor(rs, 32);
    lrow += rs;

    __builtin_amdgcn_s_setprio(1);
#pragma unroll
    for (int t = 0; t < KTN; ++t)
#pragma unroll
        for (int s2 = 0; s2 < 2; ++s2) {
            const int bb = s2 * 8;
            unsigned c01 = cvtpk(st[t][bb + 0], st[t][bb + 1]);
            unsigned c23 = cvtpk(st[t][bb + 2], st[t][bb + 3]);
            unsigned c45 = cvtpk(st[t][bb + 4], st[t][bb + 5]);
            unsigned c67 = cvtpk(st[t][bb + 6], st[t][bb + 7]);
            asm("v_permlane32_swap_b32 %0, %1" : "+v"(c01), "+v"(c45));
            asm("v_permlane32_swap_b32 %0, %1" : "+v"(c23), "+v"(c67));
            int4v pw;
            pw[0] = (int)c01; pw[1] = (int)c23; pw[2] = (int)c45; pw[3] = (int)c67;
            const bf16x8 pa = __builtin_bit_cast(bf16x8, pw);
            const int ksg = (kt0 + t) * 2 + s2;
#pragma unroll
            for (int dblk = 0; dblk < 2; ++dblk) {
                const bf16x8 vb = *(const bf16x8*)(
                    Vsb + (dblk * 32 + ln31) * 64 + (((2 * ksg + hi) ^ sw) * 8));
                oacc[dblk] = __builtin_amdgcn_mfma_f32_32x32x16_bf16(
                    pa, vb, oacc[dblk], 0, 0, 0);
            }
        }
    __builtin_amdgcn_s_setprio(0);
}

__global__ __launch_bounds__(256, 2) void flash_attn(
    const bf16* __restrict__ QKV, const bf16* __restrict__ VT,
    bf16* __restrict__ O)
{
    __shared__ bf16 Ks[4][64 * 64];
    __shared__ bf16 Vs[4][64 * 64];
    const int tid = threadIdx.x;
    const int ln = tid & 63, w = tid >> 6;       // 4 waves
    const int ln31 = ln & 31, hi = ln >> 5, sw = ln & 7;
    const int wg = blockIdx.x;
    const int g = wg & 31, p = wg >> 5;          // g = 2h+b -> fixed XCD per (b,h)
    const int h = g >> 1, b = g & 1;
    const int q0A = p * 64, q0B = (31 - p) * 64;

    const bf16* Qb = QKV + (size_t)b * TSEQ * NQKV + h * DKH;
    const bf16* Kb = Qb + 1024;
    const bf16* VTb = VT + (size_t)(b * NHEAD + h) * DKH * TSEQ;

    const int q1 = (w < 2 ? q0A : q0B) + (w & 1) * 32 + ln31;
    const int q2 = q0B + (w & 1) * 32 + ln31;

    bf16x8 qf1[4], qf2[4];
#pragma unroll
    for (int ks = 0; ks < 4; ++ks) {
        qf1[ks] = *(const bf16x8*)(Qb + (size_t)q1 * NQKV + ks * 16 + hi * 8);
        qf2[ks] = *(const bf16x8*)(Qb + (size_t)q2 * NQKV + ks * 16 + hi * 8);
    }
    WAIT_VM(0);   // qf complete before any DMA -> clean in-loop counts

    const int srow = (w & 1) * 32 + (ln >> 3);
    const int scol = ((ln & 7) ^ ((ln >> 3) & 7)) * 8;
    const bool stK = (w < 2);
    auto stage = [&](int buf, int kc) {
        if (stK) {
            const bf16* g2 = Kb + (size_t)(kc + srow) * NQKV + scol;
            bf16* s = &Ks[buf][(w & 1) * 32 * 64];
#pragma unroll
            for (int l = 0; l < 4; ++l)
                gll16(g2 + (size_t)(l * 8) * NQKV, s + l * 8 * 64);
        } else {
            const bf16* g2 = VTb + (size_t)srow * TSEQ + kc + scol;
            bf16* s = &Vs[buf][(w & 1) * 32 * 64];
#pragma unroll
            for (int l = 0; l < 4; ++l)
                gll16(g2 + (size_t)(l * 8) * TSEQ, s + l * 8 * 64);
        }
    };

    f32x16 oacc1[2] = {}, oacc2[2] = {};
    float l1 = 0.f, l2 = 0.f;

    const int nld = 32 - p;    // shared stream length (17..32)

    auto do_chunk = [&](int c) {
        const int kc = c * 64;
        const bf16* K = Ks[c & 3];
        const bf16* V = Vs[c & 3];
        if (c <= p) {            // phase1: full 64-key chunk, own tile
            if (w < 2 && c == p)
                tile_step<2, true >(0, kc, q1, K, V, qf1, oacc1, l1, ln31, hi, sw);
            else
                tile_step<2, false>(0, kc, q1, K, V, qf1, oacc1, l1, ln31, hi, sw);
        } else {                 // phase2: all waves on B, key-split
            const int kt0 = w >> 1;
            if (c == nld - 1)
                tile_step<1, true >(kt0, kc, q2, K, V, qf2, oacc2, l2, ln31, hi, sw);
            else
                tile_step<1, false>(kt0, kc, q2, K, V, qf2, oacc2, l2, ln31, hi, sw);
        }
    };

    stage(0, 0);
    stage(1, 64);              // nld >= 17 always
    for (int c = 0; c < nld; c += 2) {
        WAIT_VM(0);            // pair (c,c+1) landed; nothing newer in flight
        __syncthreads();       // collective visibility + prev computes done
        if (c + 2 < nld) stage((c + 2) & 3, (c + 2) * 64);
        if (c + 3 < nld) stage((c + 3) & 3, (c + 3) * 64);
        do_chunk(c);
        if (c + 1 < nld) do_chunk(c + 1);
    }
    __syncthreads();           // before epilogue LDS reuse

    // ---- epilogue: combine phase2 partials (w0->w2, w1->w3) via LDS
    float* exO = (float*)&Ks[0][0];   // 2 x 32q x 64d f32 = 16KB
    float* exL = (float*)&Vs[0][0];   // 2 x 32 f32
    if (w < 2) {
        float* dst = exO + w * 2048;
#pragma unroll
        for (int dblk = 0; dblk < 2; ++dblk)
#pragma unroll
            for (int r = 0; r < 16; ++r) {
                int q = (r & 3) + 8 * (r >> 2) + 4 * hi;
                dst[q * 64 + dblk * 32 + ln31] = oacc2[dblk][r];
            }
        if (ln < 32) exL[w * 32 + ln] = l2;
    }
    __syncthreads();

    f32x16 oat[2];
    float lt;
    int qs;
    if (w < 2) {
        oat[0] = oacc1[0]; oat[1] = oacc1[1];
        lt = l1;
        qs = q0A + (w & 1) * 32;
    } else {
        const float* src = exO + (w - 2) * 2048;
        lt = l1 + l2 + exL[(w - 2) * 32 + ln31];
#pragma unroll
        for (int dblk = 0; dblk < 2; ++dblk)
#pragma unroll
            for (int r = 0; r < 16; ++r) {
                int q = (r & 3) + 8 * (r >> 2) + 4 * hi;
                oat[dblk][r] = oacc1[dblk][r] + oacc2[dblk][r] +
                               src[q * 64 + dblk * 32 + ln31];
            }
        qs = q0B + (w & 1) * 32;
    }

#pragma unroll
    for (int r = 0; r < 16; ++r) {
        const int crow = (r & 3) + 8 * (r >> 2) + 4 * hi;
        const float inv = 1.0f / __shfl(lt, crow);
        const int row = qs + crow;
#pragma unroll
        for (int dblk = 0; dblk < 2; ++dblk)
            O[(size_t)(b * TSEQ + row) * DMODEL + h * DKH + dblk * 32 + ln31] =
                (bf16)(oat[dblk][r] * inv);
    }
}

// ---------------------------------------------------------------- launch
extern "C" void kernel_launch(void* const* d_in, const int* in_sizes, int n_in,
                              void* d_out, int out_size, void* d_ws, size_t ws_size,
                              hipStream_t stream)
{
    const float* x  = (const float*)d_in[0];
    const float* Wq = (const float*)d_in[2];
    const float* bq = (const float*)d_in[3];
    const float* Wk = (const float*)d_in[4];
    const float* bk = (const float*)d_in[5];
    const float* Wv = (const float*)d_in[6];
    const float* bv = (const float*)d_in[7];
    const float* Wo = (const float*)d_in[8];
    const float* bo = (const float*)d_in[9];

    char* ws = (char*)d_ws;
    bf16* xb   = (bf16*)(ws);                   // 8 MB
    bf16* QKV  = (bf16*)(ws + (8u  << 20));     // 24 MB [4096][3072] (V third unused)
    bf16* VT   = (bf16*)(ws + (32u << 20));     // 8 MB, written by QKV-GEMM V blocks
    bf16* O    = (bf16*)(ws + (40u << 20));     // 8 MB
    bf16* WT   = (bf16*)(ws + (48u << 20));     // 8 MB
    float* wsBias = (float*)O;                  // 12 KB, consumed before flash writes O

    prep<<<PREP_GRID, 256, 0, stream>>>(x, Wq, Wk, Wv, Wo, bq, bk, bv,
                                        xb, WT, wsBias);

    gemm_bias_kernel<bf16, 2, true><<<768, 256, 0, stream>>>(
        xb, WT, wsBias, QKV, NQKV, VT);

    flash_attn<<<512, 256, 0, stream>>>(QKV, VT, O);

    gemm_bias_kernel<float, 1, false><<<512, 256, 0, stream>>>(
        O, WT + 3u * (1u << 20), bo, (float*)d_out, DMODEL, nullptr);
}